// Round 3
// baseline (2886.333 us; speedup 1.0000x reference)
//
#include <hip/hip_runtime.h>
#include <hip/hip_cooperative_groups.h>

namespace cg = cooperative_groups;

// LSTM S=512,B=128,IN=256,H=512 — persistent kernel, 256 blocks =
// 8 rowgroups(16 batch rows) x 32 colgroups(16 hidden cols; 4 gate-waves).
// Weights+x-fragments in registers; h exchanged via a tagged bf16 ring in
// d_ws: payload(lo16)=bf16 h, tag(hi16)=step — ONE LLC round trip, no flags.

#define SQ   512
#define BB   128
#define IN_  256
#define HH   512
#define RG   8
#define CGN  32
#define RINGHALF (BB * HH)

typedef float    f32x4 __attribute__((ext_vector_type(4)));
typedef short    s16x8 __attribute__((ext_vector_type(8)));
typedef unsigned u32x4 __attribute__((ext_vector_type(4)));

struct P {
  const float *x, *h0, *c0;
  const float *W[4], *bW[4], *U[4], *bU[4];   // gate order f,i,o,g
  float* out;          // [SQ][BB][HH] h_seq, then [BB][HH] h, then [BB][HH] c
  unsigned* ring;      // [2][BB][HH] tagged bf16 h (lo16=payload, hi16=tag)
  int mode;            // 0 = ring protocol, 1 = gridsync fallback (no ws)
};

__device__ __forceinline__ unsigned f2b(float f) {
  unsigned u = __float_as_uint(f);
  return (u + 0x7FFFu + ((u >> 16) & 1u)) >> 16;   // RNE f32->bf16
}
__device__ __forceinline__ float sigm(float x) { return 1.f / (1.f + __expf(-x)); }
__device__ __forceinline__ float tanh_(float x) {
  float e = __expf(-2.f * fabsf(x));
  float t = (1.f - e) / (1.f + e);
  return copysignf(t, x);
}
__device__ __forceinline__ u32x4 llc_load16(const unsigned* q) {
  u32x4 v;
  asm volatile("global_load_dwordx4 %0, %1, off sc0 sc1\n\ts_waitcnt vmcnt(0)"
               : "=v"(v) : "v"(q) : "memory");
  return v;
}

__global__ void __launch_bounds__(256, 1) lstm_all(P p) {
  __shared__ unsigned short Hs[16][544];   // h bf16 tile, XOR-swizzled, stride 1088B
  __shared__ float gbuf[4][16][17];

  const int tid = threadIdx.x;
  const int bid = blockIdx.x;
  const int r   = bid & 7;          // rowgroup (round-robin -> one XCD, perf only)
  const int cgi = bid >> 3;         // colgroup
  const int rb  = r * 16;
  const int hcb = cgi * 16;

  const int w   = tid >> 6;         // wave = gate (0=f,1=i,2=o,3=g)
  const int l   = tid & 63;
  const int l16 = l & 15;
  const int lk  = l >> 4;
  const int row16 = tid >> 4;       // staging/update row 0..15
  const int n16   = tid & 15;

  // ---- per-wave B fragments (W|U) -> registers, bf16, once ----
  const int col = hcb + l16;
  s16x8 bfrag[24];
#pragma unroll
  for (int kk = 0; kk < 24; ++kk) {
    int k = kk * 32 + lk * 8;
    const float* src = (kk < 8) ? (p.W[w] + (size_t)col * IN_ + k)
                                : (p.U[w] + (size_t)col * HH + (k - IN_));
    f32x4 a = *(const f32x4*)src;
    f32x4 b = *(const f32x4*)(src + 4);
    s16x8 v;
    v[0]=(short)f2b(a.x); v[1]=(short)f2b(a.y); v[2]=(short)f2b(a.z); v[3]=(short)f2b(a.w);
    v[4]=(short)f2b(b.x); v[5]=(short)f2b(b.y); v[6]=(short)f2b(b.z); v[7]=(short)f2b(b.w);
    bfrag[kk] = v;
  }
  const float bias = p.bW[w][col] + p.bU[w][col];
  float cval = p.c0[(size_t)(rb + row16) * HH + hcb + n16];

  const float* xlane = p.x + (size_t)(rb + l16) * IN_ + lk * 8;  // + t*BB*IN_ per step

  for (int t = 0; t < SQ; ++t) {
    // ---- A) issue x loads for this step (registers; off critical path) ----
    const float* xrow = xlane + (size_t)t * BB * IN_;
    f32x4 xa[8], xb[8];
#pragma unroll
    for (int kk = 0; kk < 8; ++kk) {
      xa[kk] = *(const f32x4*)(xrow + kk * 32);
      xb[kk] = *(const f32x4*)(xrow + kk * 32 + 4);
    }

    // ---- B) obtain h_{t-1} into Hs (bf16, swizzled) ----
    if (t == 0) {
      const float* src = p.h0 + (size_t)(rb + row16) * HH + n16 * 32;
#pragma unroll
      for (int cc = 0; cc < 8; ++cc) {
        f32x4 v = *(const f32x4*)(src + cc * 4);
        unsigned lo = f2b(v.x) | (f2b(v.y) << 16);
        unsigned hi = f2b(v.z) | (f2b(v.w) << 16);
        int sidx = (n16 * 32 + cc * 4) ^ ((row16 & 7) << 3);
        *(uint2*)&Hs[row16][sidx] = make_uint2(lo, hi);
      }
    } else if (p.mode == 0) {
      // tagged ring: ONE speculative LLC round trip, retry stale chunks
      const unsigned* hb = p.ring + (((t - 1) & 1) ? RINGHALF : 0)
                         + (size_t)(rb + row16) * HH + n16 * 32;
      u32x4 c0,c1,c2,c3,c4,c5,c6,c7;
      asm volatile(
        "global_load_dwordx4 %0, %8, off sc0 sc1\n\t"
        "global_load_dwordx4 %1, %8, off offset:16 sc0 sc1\n\t"
        "global_load_dwordx4 %2, %8, off offset:32 sc0 sc1\n\t"
        "global_load_dwordx4 %3, %8, off offset:48 sc0 sc1\n\t"
        "global_load_dwordx4 %4, %8, off offset:64 sc0 sc1\n\t"
        "global_load_dwordx4 %5, %8, off offset:80 sc0 sc1\n\t"
        "global_load_dwordx4 %6, %8, off offset:96 sc0 sc1\n\t"
        "global_load_dwordx4 %7, %8, off offset:112 sc0 sc1\n\t"
        "s_waitcnt vmcnt(0)"
        : "=&v"(c0), "=&v"(c1), "=&v"(c2), "=&v"(c3),
          "=&v"(c4), "=&v"(c5), "=&v"(c6), "=&v"(c7)
        : "v"(hb) : "memory");
      const unsigned tg = (unsigned)t;
#define CHK(v) (((v).x >> 16) == tg && ((v).y >> 16) == tg && \
                ((v).z >> 16) == tg && ((v).w >> 16) == tg)
      int guard = 0;
      for (;;) {
        bool ok = true;
        if (!CHK(c0)) { ok = false; c0 = llc_load16(hb);      }
        if (!CHK(c1)) { ok = false; c1 = llc_load16(hb + 4);  }
        if (!CHK(c2)) { ok = false; c2 = llc_load16(hb + 8);  }
        if (!CHK(c3)) { ok = false; c3 = llc_load16(hb + 12); }
        if (!CHK(c4)) { ok = false; c4 = llc_load16(hb + 16); }
        if (!CHK(c5)) { ok = false; c5 = llc_load16(hb + 20); }
        if (!CHK(c6)) { ok = false; c6 = llc_load16(hb + 24); }
        if (!CHK(c7)) { ok = false; c7 = llc_load16(hb + 28); }
        if (ok) break;
        if (++guard > (1 << 18)) break;   // fail loud, never hang
      }
#undef CHK
      u32x4 cv[8] = {c0,c1,c2,c3,c4,c5,c6,c7};
#pragma unroll
      for (int cc = 0; cc < 8; ++cc) {
        unsigned lo = (cv[cc].x & 0xFFFFu) | (cv[cc].y << 16);
        unsigned hi = (cv[cc].z & 0xFFFFu) | (cv[cc].w << 16);
        int sidx = (n16 * 32 + cc * 4) ^ ((row16 & 7) << 3);
        *(uint2*)&Hs[row16][sidx] = make_uint2(lo, hi);
      }
    } else {
      // fallback: grid-wide sync + f32 h from d_out via LLC
      cg::this_grid().sync();
      const float* hrow = p.out + ((size_t)(t - 1) * BB + rb + row16) * HH + n16 * 32;
      f32x4 a0,a1,a2,a3,a4,a5,a6,a7;
      asm volatile(
        "global_load_dwordx4 %0, %8, off sc0 sc1\n\t"
        "global_load_dwordx4 %1, %8, off offset:16 sc0 sc1\n\t"
        "global_load_dwordx4 %2, %8, off offset:32 sc0 sc1\n\t"
        "global_load_dwordx4 %3, %8, off offset:48 sc0 sc1\n\t"
        "global_load_dwordx4 %4, %8, off offset:64 sc0 sc1\n\t"
        "global_load_dwordx4 %5, %8, off offset:80 sc0 sc1\n\t"
        "global_load_dwordx4 %6, %8, off offset:96 sc0 sc1\n\t"
        "global_load_dwordx4 %7, %8, off offset:112 sc0 sc1\n\t"
        "s_waitcnt vmcnt(0)"
        : "=&v"(a0), "=&v"(a1), "=&v"(a2), "=&v"(a3),
          "=&v"(a4), "=&v"(a5), "=&v"(a6), "=&v"(a7)
        : "v"(hrow) : "memory");
      f32x4 av[8] = {a0,a1,a2,a3,a4,a5,a6,a7};
#pragma unroll
      for (int cc = 0; cc < 8; ++cc) {
        unsigned lo = f2b(av[cc].x) | (f2b(av[cc].y) << 16);
        unsigned hi = f2b(av[cc].z) | (f2b(av[cc].w) << 16);
        int sidx = (n16 * 32 + cc * 4) ^ ((row16 & 7) << 3);
        *(uint2*)&Hs[row16][sidx] = make_uint2(lo, hi);
      }
    }

    // ---- C) x part: cvt + 8 MFMAs from registers (no LDS, no barrier) ----
    s16x8 xf[8];
#pragma unroll
    for (int kk = 0; kk < 8; ++kk) {
      s16x8 v;
      v[0]=(short)f2b(xa[kk].x); v[1]=(short)f2b(xa[kk].y);
      v[2]=(short)f2b(xa[kk].z); v[3]=(short)f2b(xa[kk].w);
      v[4]=(short)f2b(xb[kk].x); v[5]=(short)f2b(xb[kk].y);
      v[6]=(short)f2b(xb[kk].z); v[7]=(short)f2b(xb[kk].w);
      xf[kk] = v;
    }
    f32x4 acc0 = { bias, bias, bias, bias };
    f32x4 acc1 = { 0.f, 0.f, 0.f, 0.f };
#pragma unroll
    for (int kk = 0; kk < 8; kk += 2) {
      acc0 = __builtin_amdgcn_mfma_f32_16x16x32_bf16(xf[kk],     bfrag[kk],     acc0, 0, 0, 0);
      acc1 = __builtin_amdgcn_mfma_f32_16x16x32_bf16(xf[kk + 1], bfrag[kk + 1], acc1, 0, 0, 0);
    }

    __syncthreads();   // Hs ready

    // ---- D) h part: 16 MFMAs from swizzled LDS ----
#pragma unroll
    for (int kp = 0; kp < 16; kp += 2) {
      int off0 = (kp * 32 + lk * 8)       ^ ((l16 & 7) << 3);
      int off1 = ((kp + 1) * 32 + lk * 8) ^ ((l16 & 7) << 3);
      s16x8 a0 = *(const s16x8*)&Hs[l16][off0];
      s16x8 a1 = *(const s16x8*)&Hs[l16][off1];
      acc0 = __builtin_amdgcn_mfma_f32_16x16x32_bf16(a0, bfrag[8 + kp], acc0, 0, 0, 0);
      acc1 = __builtin_amdgcn_mfma_f32_16x16x32_bf16(a1, bfrag[9 + kp], acc1, 0, 0, 0);
    }

    // ---- E) activations -> gbuf (D-frag: row=lk*4+rr, col=l16) ----
#pragma unroll
    for (int rr = 0; rr < 4; ++rr) {
      float v = acc0[rr] + acc1[rr];
      v = (w < 3) ? sigm(v) : tanh_(v);
      gbuf[w][lk * 4 + rr][l16] = v;
    }
    __syncthreads();

    // ---- F) cell update + publish ----
    float f = gbuf[0][row16][n16];
    float i = gbuf[1][row16][n16];
    float o = gbuf[2][row16][n16];
    float g = gbuf[3][row16][n16];
    cval = f * cval + i * g;
    float h = o * tanh_(cval);

    size_t oidx = ((size_t)t * BB + rb + row16) * HH + hcb + n16;
    if (p.mode == 0) {
      unsigned tw = ((unsigned)(t + 1) << 16) | f2b(h);
      unsigned* dst = p.ring + ((t & 1) ? RINGHALF : 0)
                    + (size_t)(rb + row16) * HH + hcb + n16;
      asm volatile("global_store_dword %0, %1, off sc0 sc1"
                   :: "v"(dst), "v"(tw) : "memory");
      __builtin_nontemporal_store(h, p.out + oidx);
    } else {
      asm volatile("global_store_dword %0, %1, off sc0 sc1"
                   :: "v"(p.out + oidx), "v"(h) : "memory");
      asm volatile("s_waitcnt vmcnt(0)" ::: "memory");
    }
    if (t == SQ - 1) {
      size_t base = (size_t)SQ * BB * HH;
      size_t idx2 = (size_t)(rb + row16) * HH + hcb + n16;
      p.out[base + idx2] = h;
      p.out[base + (size_t)BB * HH + idx2] = cval;
    }
    // no trailing barrier: next iter's pre-MFMA __syncthreads covers gbuf/Hs reuse
  }
}

extern "C" void kernel_launch(void* const* d_in, const int* in_sizes, int n_in,
                              void* d_out, int out_size, void* d_ws, size_t ws_size,
                              hipStream_t stream) {
  P p;
  p.x  = (const float*)d_in[0];
  p.h0 = (const float*)d_in[1];
  p.c0 = (const float*)d_in[2];
  for (int g = 0; g < 4; ++g) {
    p.W[g]  = (const float*)d_in[3 + 4 * g];
    p.bW[g] = (const float*)d_in[4 + 4 * g];
    p.U[g]  = (const float*)d_in[5 + 4 * g];
    p.bU[g] = (const float*)d_in[6 + 4 * g];
  }
  p.out = (float*)d_out;

  const size_t need = (size_t)2 * BB * HH * sizeof(unsigned);   // 512 KB ring
  const bool ws_ok = (d_ws != nullptr) && (ws_size >= need);
  p.mode = ws_ok ? 0 : 1;
  p.ring = ws_ok ? (unsigned*)d_ws : nullptr;
  if (ws_ok) hipMemsetAsync(d_ws, 0, need, stream);   // tags=0: never a valid step tag

  void* args[] = { &p };
  hipError_t e = hipLaunchCooperativeKernel((const void*)lstm_all,
                                            dim3(RG * CGN), dim3(256),
                                            args, 0, stream);
  if (e != hipSuccess) {
    // plain launch: 256 blocks at 1/CU are co-resident; ring protocol still valid
    hipLaunchKernelGGL(lstm_all, dim3(RG * CGN), dim3(256), 0, stream, p);
  }
}

// Round 4
// 1949.030 us; speedup vs baseline: 1.4809x; 1.4809x over previous
//
#include <hip/hip_runtime.h>
#include <hip/hip_cooperative_groups.h>

namespace cg = cooperative_groups;

// LSTM S=512,B=128,IN=256,H=512 — persistent kernel, 256 blocks =
// 8 rowgroups(16 batch rows, one XCD each under round-robin) x 32 colgroups.
// Weights + x-fragments in registers; h exchanged via tagged bf16 ring:
//   - XCD placement verified via HW_REG_XCC_ID exchange at startup
//   - uniform rowgroup -> L2-local ring (sc0 only, ~200cy visibility)
//   - otherwise        -> LLC ring (sc0 sc1, proven in rounds 2-3)
// Retry rounds reload all 8 chunks with ONE waitcnt (1 round trip per round).

#define SQ   512
#define BB   128
#define IN_  256
#define HH   512
#define RG   8
#define CGN  32
#define RINGHALF (BB * HH)     // dwords
#define RING_OFF 1024          // dwords (4 KB head for ids)

typedef float    f32x4 __attribute__((ext_vector_type(4)));
typedef short    s16x8 __attribute__((ext_vector_type(8)));
typedef unsigned u32x4 __attribute__((ext_vector_type(4)));

struct P {
  const float *x, *h0, *c0;
  const float *W[4], *bW[4], *U[4], *bU[4];   // gate order f,i,o,g
  float* out;        // [SQ][BB][HH] h_seq, then [BB][HH] h, then [BB][HH] c
  unsigned* ws;      // [0,1024): tagged xcc ids; [1024,...): ring [2][BB][HH]
  int mode;          // 0 = ring protocol, 2 = gridsync fallback (no ws)
};

__device__ __forceinline__ unsigned f2b(float f) {
  unsigned u = __float_as_uint(f);
  return (u + 0x7FFFu + ((u >> 16) & 1u)) >> 16;   // RNE f32->bf16
}
__device__ __forceinline__ float sigm(float x) { return 1.f / (1.f + __expf(-x)); }
__device__ __forceinline__ float tanh_(float x) {
  float e = __expf(-2.f * fabsf(x));
  float t = (1.f - e) / (1.f + e);
  return copysignf(t, x);
}

// 8x dwordx4 from base+{0,256,...,1792}B, ONE waitcnt. L2-local (sc0) variant.
#define LOAD8_L2(c0_,c1_,c2_,c3_,c4_,c5_,c6_,c7_,ptr_)                       \
  asm volatile(                                                              \
    "global_load_dwordx4 %0, %8, off sc0\n\t"                                \
    "global_load_dwordx4 %1, %8, off offset:256 sc0\n\t"                     \
    "global_load_dwordx4 %2, %8, off offset:512 sc0\n\t"                     \
    "global_load_dwordx4 %3, %8, off offset:768 sc0\n\t"                     \
    "global_load_dwordx4 %4, %8, off offset:1024 sc0\n\t"                    \
    "global_load_dwordx4 %5, %8, off offset:1280 sc0\n\t"                    \
    "global_load_dwordx4 %6, %8, off offset:1536 sc0\n\t"                    \
    "global_load_dwordx4 %7, %8, off offset:1792 sc0\n\t"                    \
    "s_waitcnt vmcnt(0)"                                                     \
    : "=&v"(c0_), "=&v"(c1_), "=&v"(c2_), "=&v"(c3_),                        \
      "=&v"(c4_), "=&v"(c5_), "=&v"(c6_), "=&v"(c7_)                         \
    : "v"(ptr_) : "memory")

#define LOAD8_LLC(c0_,c1_,c2_,c3_,c4_,c5_,c6_,c7_,ptr_)                      \
  asm volatile(                                                              \
    "global_load_dwordx4 %0, %8, off sc0 sc1\n\t"                            \
    "global_load_dwordx4 %1, %8, off offset:256 sc0 sc1\n\t"                 \
    "global_load_dwordx4 %2, %8, off offset:512 sc0 sc1\n\t"                 \
    "global_load_dwordx4 %3, %8, off offset:768 sc0 sc1\n\t"                 \
    "global_load_dwordx4 %4, %8, off offset:1024 sc0 sc1\n\t"                \
    "global_load_dwordx4 %5, %8, off offset:1280 sc0 sc1\n\t"                \
    "global_load_dwordx4 %6, %8, off offset:1536 sc0 sc1\n\t"                \
    "global_load_dwordx4 %7, %8, off offset:1792 sc0 sc1\n\t"                \
    "s_waitcnt vmcnt(0)"                                                     \
    : "=&v"(c0_), "=&v"(c1_), "=&v"(c2_), "=&v"(c3_),                        \
      "=&v"(c4_), "=&v"(c5_), "=&v"(c6_), "=&v"(c7_)                         \
    : "v"(ptr_) : "memory")

__global__ void __launch_bounds__(256, 1) lstm_all(P p) {
  __shared__ unsigned short Hs[16][512];   // h bf16, byte-XOR swizzled rows
  __shared__ float gbuf[4][16][17];
  __shared__ int mode_sh;

  const int tid = threadIdx.x;
  const int bid = blockIdx.x;
  const int r   = bid & 7;          // rowgroup (round-robin -> one XCD; VERIFIED)
  const int cgi = bid >> 3;         // colgroup
  const int rb  = r * 16;
  const int hcb = cgi * 16;

  const int w   = tid >> 6;         // wave = gate (0=f,1=i,2=o,3=g)
  const int l   = tid & 63;
  const int l16 = l & 15;
  const int lk  = l >> 4;
  const int row16 = tid >> 4;       // staging/update row 0..15
  const int n16   = tid & 15;

  unsigned* ids  = p.ws;                       // valid only in mode 0
  unsigned* ring = p.ws + RING_OFF;

  // ---- startup: publish XCC id, verify rowgroup-on-one-XCD placement ----
  if (p.mode == 0) {
    unsigned xcc;
    asm volatile("s_getreg_b32 %0, hwreg(20, 0, 4)" : "=s"(xcc));  // HW_REG_XCC_ID
    if (tid == 0) {
      unsigned v = 0x10000u | xcc;
      asm volatile("global_store_dword %0, %1, off sc0 sc1"
                   :: "v"(ids + (r * 32 + cgi)), "v"(v) : "memory");
    }
    if (tid < 64) {    // wave 0: each lane polls 4 ids (256 total)
      const unsigned* q = ids + l * 4;
      u32x4 c;
      int guard = 0;
      for (;;) {
        asm volatile("global_load_dwordx4 %0, %1, off sc0 sc1\n\ts_waitcnt vmcnt(0)"
                     : "=v"(c) : "v"(q) : "memory");
        bool fresh = ((c.x >> 16) == 1) && ((c.y >> 16) == 1) &&
                     ((c.z >> 16) == 1) && ((c.w >> 16) == 1);
        if (__all(fresh)) break;
        if (++guard > (1 << 20)) break;
        __builtin_amdgcn_s_sleep(1);
      }
      unsigned i0 = c.x & 0xFFFFu, i1 = c.y & 0xFFFFu,
               i2 = c.z & 0xFFFFu, i3 = c.w & 0xFFFFu;
      bool four_eq = (i0 == i1) && (i0 == i2) && (i0 == i3);
      unsigned ref = __shfl(i0, (l >> 3) << 3);       // rowgroup-leader lane
      bool groupeq = four_eq && (i0 == ref);
      unsigned long long eqm = __ballot(groupeq);
      unsigned gref = __shfl(i0, 0);
      bool dif = (i0 != gref) || (i1 != gref) || (i2 != gref) || (i3 != gref);
      bool anydiff = __ballot(dif) != 0ull;   // rejects bogus constant register
      bool rguni = ((eqm >> (r * 8)) & 0xFFull) == 0xFFull;
      if (tid == 0) mode_sh = (rguni && anydiff) ? 1 : 0;
    }
  } else if (tid == 0) {
    mode_sh = 0;
  }

  // ---- per-wave B fragments (W|U) -> registers, bf16, once ----
  const int col = hcb + l16;
  s16x8 bfrag[24];
#pragma unroll
  for (int kk = 0; kk < 24; ++kk) {
    int k = kk * 32 + lk * 8;
    const float* src = (kk < 8) ? (p.W[w] + (size_t)col * IN_ + k)
                                : (p.U[w] + (size_t)col * HH + (k - IN_));
    f32x4 a = *(const f32x4*)src;
    f32x4 b = *(const f32x4*)(src + 4);
    s16x8 v;
    v[0]=(short)f2b(a.x); v[1]=(short)f2b(a.y); v[2]=(short)f2b(a.z); v[3]=(short)f2b(a.w);
    v[4]=(short)f2b(b.x); v[5]=(short)f2b(b.y); v[6]=(short)f2b(b.z); v[7]=(short)f2b(b.w);
    bfrag[kk] = v;
  }
  const float bias = p.bW[w][col] + p.bU[w][col];
  float cval = p.c0[(size_t)(rb + row16) * HH + hcb + n16];

  __syncthreads();
  const bool l2m = (mode_sh == 1);

  const float* xlane = p.x + (size_t)(rb + l16) * IN_ + lk * 8;
  const int wswz = (row16 & 7) << 4;   // staging-row byte-XOR key
  const int rswz = (l16 & 7) << 4;     // mfma-read byte-XOR key
  char* HsB = (char*)&Hs[0][0];

  for (int t = 0; t < SQ; ++t) {
    // ---- A) issue x loads (registers; latency hides under the poll) ----
    const float* xrow = xlane + (size_t)t * BB * IN_;
    f32x4 xa[8], xb[8];
#pragma unroll
    for (int kk = 0; kk < 8; ++kk) {
      xa[kk] = *(const f32x4*)(xrow + kk * 32);
      xb[kk] = *(const f32x4*)(xrow + kk * 32 + 4);
    }

    // ---- B) obtain h_{t-1} into Hs (bf16, swizzled) ----
    // staging thread (row16,n16), chunk cc: elements k = cc*64 + n16*4
    if (t == 0) {
      const float* src = p.h0 + (size_t)(rb + row16) * HH + n16 * 4;
#pragma unroll
      for (int cc = 0; cc < 8; ++cc) {
        f32x4 v = *(const f32x4*)(src + cc * 64);
        unsigned lo = f2b(v.x) | (f2b(v.y) << 16);
        unsigned hi = f2b(v.z) | (f2b(v.w) << 16);
        int boff = ((cc * 128 + n16 * 8) ^ wswz);
        *(uint2*)(HsB + row16 * 1024 + boff) = make_uint2(lo, hi);
      }
    } else if (p.mode == 0) {
      const unsigned* hb = ring + (((t - 1) & 1) ? RINGHALF : 0)
                         + (size_t)(rb + row16) * HH + n16 * 4;
      u32x4 c0,c1,c2,c3,c4,c5,c6,c7;
      const unsigned tg = (unsigned)t;
#define TAGOK(v) (((v).x >> 16) == tg && ((v).y >> 16) == tg && \
                  ((v).z >> 16) == tg && ((v).w >> 16) == tg)
      int spin = 0;
      for (;;) {
        if (l2m) { LOAD8_L2 (c0,c1,c2,c3,c4,c5,c6,c7,hb); }
        else     { LOAD8_LLC(c0,c1,c2,c3,c4,c5,c6,c7,hb); }
        if (TAGOK(c0) && TAGOK(c1) && TAGOK(c2) && TAGOK(c3) &&
            TAGOK(c4) && TAGOK(c5) && TAGOK(c6) && TAGOK(c7)) break;
        if (++spin > (1 << 18)) break;     // fail loud, never hang
        if (spin > 2) __builtin_amdgcn_s_sleep(1);
      }
#undef TAGOK
      u32x4 cv[8] = {c0,c1,c2,c3,c4,c5,c6,c7};
#pragma unroll
      for (int cc = 0; cc < 8; ++cc) {
        unsigned lo = (cv[cc].x & 0xFFFFu) | (cv[cc].y << 16);
        unsigned hi = (cv[cc].z & 0xFFFFu) | (cv[cc].w << 16);
        int boff = ((cc * 128 + n16 * 8) ^ wswz);
        *(uint2*)(HsB + row16 * 1024 + boff) = make_uint2(lo, hi);
      }
    } else {
      // gridsync fallback: f32 h from d_out via LLC
      cg::this_grid().sync();
      const float* hrow = p.out + ((size_t)(t - 1) * BB + rb + row16) * HH + n16 * 4;
      u32x4 a0,a1,a2,a3,a4,a5,a6,a7;
      LOAD8_LLC(a0,a1,a2,a3,a4,a5,a6,a7,hrow);
      u32x4 av[8] = {a0,a1,a2,a3,a4,a5,a6,a7};
#pragma unroll
      for (int cc = 0; cc < 8; ++cc) {
        unsigned lo = f2b(__uint_as_float(av[cc].x)) | (f2b(__uint_as_float(av[cc].y)) << 16);
        unsigned hi = f2b(__uint_as_float(av[cc].z)) | (f2b(__uint_as_float(av[cc].w)) << 16);
        int boff = ((cc * 128 + n16 * 8) ^ wswz);
        *(uint2*)(HsB + row16 * 1024 + boff) = make_uint2(lo, hi);
      }
    }

    // ---- C) x part: cvt + 8 MFMAs from registers ----
    s16x8 xf[8];
#pragma unroll
    for (int kk = 0; kk < 8; ++kk) {
      s16x8 v;
      v[0]=(short)f2b(xa[kk].x); v[1]=(short)f2b(xa[kk].y);
      v[2]=(short)f2b(xa[kk].z); v[3]=(short)f2b(xa[kk].w);
      v[4]=(short)f2b(xb[kk].x); v[5]=(short)f2b(xb[kk].y);
      v[6]=(short)f2b(xb[kk].z); v[7]=(short)f2b(xb[kk].w);
      xf[kk] = v;
    }
    f32x4 acc0 = { bias, bias, bias, bias };
    f32x4 acc1 = { 0.f, 0.f, 0.f, 0.f };
#pragma unroll
    for (int kk = 0; kk < 8; kk += 2) {
      acc0 = __builtin_amdgcn_mfma_f32_16x16x32_bf16(xf[kk],     bfrag[kk],     acc0, 0, 0, 0);
      acc1 = __builtin_amdgcn_mfma_f32_16x16x32_bf16(xf[kk + 1], bfrag[kk + 1], acc1, 0, 0, 0);
    }

    __syncthreads();   // Hs ready

    // ---- D) h part: 16 MFMAs; lane reads A[row=l16][k=kp*32+lk*8+j] ----
#pragma unroll
    for (int kp = 0; kp < 16; kp += 2) {
      int b0 = ((kp * 64 + lk * 16)       ^ rswz);
      int b1 = (((kp + 1) * 64 + lk * 16) ^ rswz);
      s16x8 a0 = *(const s16x8*)(HsB + l16 * 1024 + b0);
      s16x8 a1 = *(const s16x8*)(HsB + l16 * 1024 + b1);
      acc0 = __builtin_amdgcn_mfma_f32_16x16x32_bf16(a0, bfrag[8 + kp], acc0, 0, 0, 0);
      acc1 = __builtin_amdgcn_mfma_f32_16x16x32_bf16(a1, bfrag[9 + kp], acc1, 0, 0, 0);
    }

    // ---- E) activations -> gbuf (D-frag: row=lk*4+rr, col=l16) ----
#pragma unroll
    for (int rr = 0; rr < 4; ++rr) {
      float v = acc0[rr] + acc1[rr];
      v = (w < 3) ? sigm(v) : tanh_(v);
      gbuf[w][lk * 4 + rr][l16] = v;
    }
    __syncthreads();

    // ---- F) cell update + publish ----
    float f = gbuf[0][row16][n16];
    float i = gbuf[1][row16][n16];
    float o = gbuf[2][row16][n16];
    float g = gbuf[3][row16][n16];
    cval = f * cval + i * g;
    float h = o * tanh_(cval);

    size_t oidx = ((size_t)t * BB + rb + row16) * HH + hcb + n16;
    if (p.mode == 0) {
      unsigned tw = ((unsigned)(t + 1) << 16) | f2b(h);
      unsigned* dst = ring + ((t & 1) ? RINGHALF : 0)
                    + (size_t)(rb + row16) * HH + hcb + n16;
      if (l2m) {
        asm volatile("global_store_dword %0, %1, off sc0"
                     :: "v"(dst), "v"(tw) : "memory");
      } else {
        asm volatile("global_store_dword %0, %1, off sc0 sc1"
                     :: "v"(dst), "v"(tw) : "memory");
      }
      __builtin_nontemporal_store(h, p.out + oidx);
    } else {
      asm volatile("global_store_dword %0, %1, off sc0 sc1"
                   :: "v"(p.out + oidx), "v"(h) : "memory");
      asm volatile("s_waitcnt vmcnt(0)" ::: "memory");
    }
    if (t == SQ - 1) {
      size_t base = (size_t)SQ * BB * HH;
      size_t idx2 = (size_t)(rb + row16) * HH + hcb + n16;
      p.out[base + idx2] = h;
      p.out[base + (size_t)BB * HH + idx2] = cval;
    }
    // next iteration's post-staging __syncthreads covers Hs/gbuf reuse
  }
}

extern "C" void kernel_launch(void* const* d_in, const int* in_sizes, int n_in,
                              void* d_out, int out_size, void* d_ws, size_t ws_size,
                              hipStream_t stream) {
  P p;
  p.x  = (const float*)d_in[0];
  p.h0 = (const float*)d_in[1];
  p.c0 = (const float*)d_in[2];
  for (int g = 0; g < 4; ++g) {
    p.W[g]  = (const float*)d_in[3 + 4 * g];
    p.bW[g] = (const float*)d_in[4 + 4 * g];
    p.U[g]  = (const float*)d_in[5 + 4 * g];
    p.bU[g] = (const float*)d_in[6 + 4 * g];
  }
  p.out = (float*)d_out;

  const size_t need = (size_t)(RING_OFF + 2 * BB * HH) * sizeof(unsigned);
  const bool ws_ok = (d_ws != nullptr) && (ws_size >= need);
  p.mode = ws_ok ? 0 : 2;
  p.ws   = ws_ok ? (unsigned*)d_ws : nullptr;
  if (ws_ok) hipMemsetAsync(d_ws, 0, need, stream);  // tags=0, ids cleared

  void* args[] = { &p };
  hipError_t e = hipLaunchCooperativeKernel((const void*)lstm_all,
                                            dim3(RG * CGN), dim3(256),
                                            args, 0, stream);
  if (e != hipSuccess) {
    // plain launch: 256 blocks at 1/CU are co-resident; ring protocol valid
    hipLaunchKernelGGL(lstm_all, dim3(RG * CGN), dim3(256), 0, stream, p);
  }
}

// Round 8
// 1297.530 us; speedup vs baseline: 2.2245x; 1.5021x over previous
//
#include <hip/hip_runtime.h>
#include <hip/hip_cooperative_groups.h>

namespace cg = cooperative_groups;

// LSTM S=512,B=128,IN=256,H=512 — persistent kernel, 256 blocks =
// 8 rowgroups(16 batch rows) x 32 colgroups(16 hidden cols; 4 gate-waves).
// Round 8: ALWAYS-LLC tagged bf16 ring (re-validated across graph replays in
// rounds 2/3/4; self-healing — tag travels with data; stale tags from a prior
// replay carry identical deterministic payloads, so they are harmless).
// L2-local mode REMOVED (cross-replay stale-L2 hazard caused round 7's
// re-validation failure). Keeps x-LDS dedup + x prefetch.

#define SQ   512
#define BB   128
#define IN_  256
#define HH   512
#define RG   8
#define CGN  32
#define RINGHALF (BB * HH)     // dwords
#define RING_OFF 1024          // dwords (4 KB head, unused)

typedef float    f32x4 __attribute__((ext_vector_type(4)));
typedef short    s16x8 __attribute__((ext_vector_type(8)));
typedef unsigned u32x4 __attribute__((ext_vector_type(4)));

struct P {
  const float *x, *h0, *c0;
  const float *W[4], *bW[4], *U[4], *bU[4];   // gate order f,i,o,g
  float* out;        // [SQ][BB][HH] h_seq, then [BB][HH] h, then [BB][HH] c
  unsigned* ring;    // [2][BB][HH] tagged bf16 h (lo16=payload, hi16=tag)
  int mode;          // 0 = ring protocol, 2 = gridsync fallback (no ws)
};

__device__ __forceinline__ unsigned f2b(float f) {
  unsigned u = __float_as_uint(f);
  return (u + 0x7FFFu + ((u >> 16) & 1u)) >> 16;   // RNE f32->bf16
}
__device__ __forceinline__ float sigm(float x) { return 1.f / (1.f + __expf(-x)); }
__device__ __forceinline__ float tanh_(float x) {
  float e = __expf(-2.f * fabsf(x));
  float t = (1.f - e) / (1.f + e);
  return copysignf(t, x);
}
__device__ __forceinline__ u32x4 pack8(f32x4 a, f32x4 b) {
  u32x4 d;
  d.x = f2b(a.x) | (f2b(a.y) << 16);
  d.y = f2b(a.z) | (f2b(a.w) << 16);
  d.z = f2b(b.x) | (f2b(b.y) << 16);
  d.w = f2b(b.z) | (f2b(b.w) << 16);
  return d;
}

// 8x dwordx4 from base+{0,256,...,1792}B, ONE waitcnt, LLC-coherent.
#define LOAD8_LLC(c0_,c1_,c2_,c3_,c4_,c5_,c6_,c7_,ptr_)                      \
  asm volatile(                                                              \
    "global_load_dwordx4 %0, %8, off sc0 sc1\n\t"                            \
    "global_load_dwordx4 %1, %8, off offset:256 sc0 sc1\n\t"                 \
    "global_load_dwordx4 %2, %8, off offset:512 sc0 sc1\n\t"                 \
    "global_load_dwordx4 %3, %8, off offset:768 sc0 sc1\n\t"                 \
    "global_load_dwordx4 %4, %8, off offset:1024 sc0 sc1\n\t"                \
    "global_load_dwordx4 %5, %8, off offset:1280 sc0 sc1\n\t"                \
    "global_load_dwordx4 %6, %8, off offset:1536 sc0 sc1\n\t"                \
    "global_load_dwordx4 %7, %8, off offset:1792 sc0 sc1\n\t"                \
    "s_waitcnt vmcnt(0)"                                                     \
    : "=&v"(c0_), "=&v"(c1_), "=&v"(c2_), "=&v"(c3_),                        \
      "=&v"(c4_), "=&v"(c5_), "=&v"(c6_), "=&v"(c7_)                         \
    : "v"(ptr_) : "memory")

__global__ void __launch_bounds__(256, 1) lstm_all(P p) {
  __shared__ unsigned short Hs[16][512];      // h bf16, rows 1024B, XOR swz
  __shared__ unsigned short Xs[2][16][256];   // x bf16 double-buf, rows 512B
  __shared__ float gbuf[4][16][17];

  const int tid = threadIdx.x;
  const int bid = blockIdx.x;
  const int r   = bid & 7;          // rowgroup
  const int cgi = bid >> 3;         // colgroup
  const int rb  = r * 16;
  const int hcb = cgi * 16;

  const int w   = tid >> 6;         // wave = gate (0=f,1=i,2=o,3=g)
  const int l   = tid & 63;
  const int l16 = l & 15;
  const int lk  = l >> 4;
  const int row16 = tid >> 4;       // staging/update row 0..15
  const int n16   = tid & 15;

  unsigned* ring = p.ring;          // valid only in mode 0

  // ---- per-wave B fragments (W|U) -> registers, bf16, once ----
  const int col = hcb + l16;
  s16x8 bfrag[24];
#pragma unroll
  for (int kk = 0; kk < 24; ++kk) {
    int k = kk * 32 + lk * 8;
    const float* src = (kk < 8) ? (p.W[w] + (size_t)col * IN_ + k)
                                : (p.U[w] + (size_t)col * HH + (k - IN_));
    f32x4 a = *(const f32x4*)src;
    f32x4 b = *(const f32x4*)(src + 4);
    s16x8 v;
    v[0]=(short)f2b(a.x); v[1]=(short)f2b(a.y); v[2]=(short)f2b(a.z); v[3]=(short)f2b(a.w);
    v[4]=(short)f2b(b.x); v[5]=(short)f2b(b.y); v[6]=(short)f2b(b.z); v[7]=(short)f2b(b.w);
    bfrag[kk] = v;
  }
  const float bias = p.bW[w][col] + p.bU[w][col];
  float cval = p.c0[(size_t)(rb + row16) * HH + hcb + n16];

  const int wswz = (row16 & 7) << 4;   // staging-row byte-XOR key
  const int rswz = (l16 & 7) << 4;     // mfma-read byte-XOR key
  char* HsB = (char*)&Hs[0][0];
  char* XsB = (char*)&Xs[0][0][0];

  // ---- prologue: x(t=0) into registers ----
  f32x4 xg0, xg1, xg2, xg3;
  {
    const float* xs = p.x + (size_t)(rb + row16) * IN_ + n16 * 16;
    xg0 = *(const f32x4*)(xs);
    xg1 = *(const f32x4*)(xs + 4);
    xg2 = *(const f32x4*)(xs + 8);
    xg3 = *(const f32x4*)(xs + 12);
  }

  for (int t = 0; t < SQ; ++t) {
    // ---- A) Xs[t&1] <- xreg; issue x(t+1) loads (hide under h poll) ----
    {
      char* xrow = XsB + (t & 1) * 8192 + row16 * 512;
      *(u32x4*)(xrow + ((n16 * 32)      ^ wswz)) = pack8(xg0, xg1);
      *(u32x4*)(xrow + ((n16 * 32 + 16) ^ wswz)) = pack8(xg2, xg3);
      if (t + 1 < SQ) {
        const float* xs = p.x + ((size_t)(t + 1) * BB + rb + row16) * IN_ + n16 * 16;
        xg0 = *(const f32x4*)(xs);
        xg1 = *(const f32x4*)(xs + 4);
        xg2 = *(const f32x4*)(xs + 8);
        xg3 = *(const f32x4*)(xs + 12);
      }
    }

    // ---- B) obtain h_{t-1} into Hs (bf16, swizzled) — tagged LLC ring ----
    char* hrow = HsB + row16 * 1024;
    if (t == 0) {
      const float* src = p.h0 + (size_t)(rb + row16) * HH + n16 * 4;
#pragma unroll
      for (int cc = 0; cc < 8; ++cc) {
        f32x4 v = *(const f32x4*)(src + cc * 64);
        unsigned lo = f2b(v.x) | (f2b(v.y) << 16);
        unsigned hi = f2b(v.z) | (f2b(v.w) << 16);
        int boff = ((cc * 128 + n16 * 8) ^ wswz);
        *(uint2*)(hrow + boff) = make_uint2(lo, hi);
      }
    } else if (p.mode == 0) {
      const unsigned* hb = ring + (((t - 1) & 1) ? RINGHALF : 0)
                         + (size_t)(rb + row16) * HH + n16 * 4;
      u32x4 c0,c1,c2,c3,c4,c5,c6,c7;
      const unsigned tg = (unsigned)t;
#define TAGOK(v) (((v).x >> 16) == tg && ((v).y >> 16) == tg && \
                  ((v).z >> 16) == tg && ((v).w >> 16) == tg)
      int spin = 0;
      for (;;) {
        LOAD8_LLC(c0,c1,c2,c3,c4,c5,c6,c7,hb);
        if (TAGOK(c0) && TAGOK(c1) && TAGOK(c2) && TAGOK(c3) &&
            TAGOK(c4) && TAGOK(c5) && TAGOK(c6) && TAGOK(c7)) break;
        if (++spin > (1 << 16)) break;   // bounded: fail loud, never hang
        if (spin > 8) __builtin_amdgcn_s_sleep(1);
      }
#undef TAGOK
      u32x4 cv[8] = {c0,c1,c2,c3,c4,c5,c6,c7};
#pragma unroll
      for (int cc = 0; cc < 8; ++cc) {
        unsigned lo = (cv[cc].x & 0xFFFFu) | (cv[cc].y << 16);
        unsigned hi = (cv[cc].z & 0xFFFFu) | (cv[cc].w << 16);
        int boff = ((cc * 128 + n16 * 8) ^ wswz);
        *(uint2*)(hrow + boff) = make_uint2(lo, hi);
      }
    } else {
      // gridsync fallback: f32 h from d_out via LLC
      cg::this_grid().sync();
      const float* hp = p.out + ((size_t)(t - 1) * BB + rb + row16) * HH + n16 * 4;
      u32x4 a0,a1,a2,a3,a4,a5,a6,a7;
      LOAD8_LLC(a0,a1,a2,a3,a4,a5,a6,a7,hp);
      u32x4 av[8] = {a0,a1,a2,a3,a4,a5,a6,a7};
#pragma unroll
      for (int cc = 0; cc < 8; ++cc) {
        unsigned lo = f2b(__uint_as_float(av[cc].x)) | (f2b(__uint_as_float(av[cc].y)) << 16);
        unsigned hi = f2b(__uint_as_float(av[cc].z)) | (f2b(__uint_as_float(av[cc].w)) << 16);
        int boff = ((cc * 128 + n16 * 8) ^ wswz);
        *(uint2*)(hrow + boff) = make_uint2(lo, hi);
      }
    }
    __syncthreads();   // Xs[t&1] + Hs ready

    // ---- D) 24 MFMAs: 8 from Xs (K=0..255), 16 from Hs (K=256..767) ----
    f32x4 acc0 = { bias, bias, bias, bias };
    f32x4 acc1 = { 0.f, 0.f, 0.f, 0.f };
    const char* xr = XsB + (t & 1) * 8192 + l16 * 512;
    const char* hr = HsB + l16 * 1024;
#pragma unroll
    for (int kp = 0; kp < 8; kp += 2) {
      s16x8 a0 = *(const s16x8*)(xr + ((kp * 64 + lk * 16)       ^ rswz));
      s16x8 a1 = *(const s16x8*)(xr + (((kp + 1) * 64 + lk * 16) ^ rswz));
      acc0 = __builtin_amdgcn_mfma_f32_16x16x32_bf16(a0, bfrag[kp],     acc0, 0, 0, 0);
      acc1 = __builtin_amdgcn_mfma_f32_16x16x32_bf16(a1, bfrag[kp + 1], acc1, 0, 0, 0);
    }
#pragma unroll
    for (int kp = 0; kp < 16; kp += 2) {
      s16x8 a0 = *(const s16x8*)(hr + ((kp * 64 + lk * 16)       ^ rswz));
      s16x8 a1 = *(const s16x8*)(hr + (((kp + 1) * 64 + lk * 16) ^ rswz));
      acc0 = __builtin_amdgcn_mfma_f32_16x16x32_bf16(a0, bfrag[8 + kp], acc0, 0, 0, 0);
      acc1 = __builtin_amdgcn_mfma_f32_16x16x32_bf16(a1, bfrag[9 + kp], acc1, 0, 0, 0);
    }

    // ---- E) activations -> gbuf (D-frag: row=lk*4+rr, col=l16) ----
#pragma unroll
    for (int rr = 0; rr < 4; ++rr) {
      float v = acc0[rr] + acc1[rr];
      v = (w < 3) ? sigm(v) : tanh_(v);
      gbuf[w][lk * 4 + rr][l16] = v;
    }
    __syncthreads();

    // ---- F) cell update + publish (tagged ring; no waitcnt needed) ----
    float f = gbuf[0][row16][n16];
    float i = gbuf[1][row16][n16];
    float o = gbuf[2][row16][n16];
    float g = gbuf[3][row16][n16];
    cval = f * cval + i * g;
    float h = o * tanh_(cval);

    size_t oidx = ((size_t)t * BB + rb + row16) * HH + hcb + n16;
    if (p.mode == 0) {
      unsigned tw = ((unsigned)(t + 1) << 16) | f2b(h);
      unsigned* dst = ring + ((t & 1) ? RINGHALF : 0)
                    + (size_t)(rb + row16) * HH + hcb + n16;
      asm volatile("global_store_dword %0, %1, off sc0 sc1"
                   :: "v"(dst), "v"(tw) : "memory");
      __builtin_nontemporal_store(h, p.out + oidx);
    } else {
      asm volatile("global_store_dword %0, %1, off sc0 sc1"
                   :: "v"(p.out + oidx), "v"(h) : "memory");
      asm volatile("s_waitcnt vmcnt(0)" ::: "memory");
    }
    if (t == SQ - 1) {
      size_t base = (size_t)SQ * BB * HH;
      size_t idx2 = (size_t)(rb + row16) * HH + hcb + n16;
      p.out[base + idx2] = h;
      p.out[base + (size_t)BB * HH + idx2] = cval;
    }
    // next iteration's post-B __syncthreads covers Hs/gbuf/Xs reuse
  }
}

extern "C" void kernel_launch(void* const* d_in, const int* in_sizes, int n_in,
                              void* d_out, int out_size, void* d_ws, size_t ws_size,
                              hipStream_t stream) {
  P p;
  p.x  = (const float*)d_in[0];
  p.h0 = (const float*)d_in[1];
  p.c0 = (const float*)d_in[2];
  for (int g = 0; g < 4; ++g) {
    p.W[g]  = (const float*)d_in[3 + 4 * g];
    p.bW[g] = (const float*)d_in[4 + 4 * g];
    p.U[g]  = (const float*)d_in[5 + 4 * g];
    p.bU[g] = (const float*)d_in[6 + 4 * g];
  }
  p.out = (float*)d_out;

  const size_t need = (size_t)(RING_OFF + 2 * BB * HH) * sizeof(unsigned);
  const bool ws_ok = (d_ws != nullptr) && (ws_size >= need);
  p.mode = ws_ok ? 0 : 2;
  p.ring = ws_ok ? ((unsigned*)d_ws + RING_OFF) : nullptr;
  if (ws_ok) hipMemsetAsync(d_ws, 0, need, stream);   // tags=0: never valid

  void* args[] = { &p };
  hipError_t e = hipLaunchCooperativeKernel((const void*)lstm_all,
                                            dim3(RG * CGN), dim3(256),
                                            args, 0, stream);
  if (e != hipSuccess) {
    // plain launch: 256 blocks at 1/CU are co-resident; ring protocol valid
    hipLaunchKernelGGL(lstm_all, dim3(RG * CGN), dim3(256), 0, stream, p);
  }
}